// Round 1
// baseline (99.627 us; speedup 1.0000x reference)
//
#include <hip/hip_runtime.h>

#define NC 21
#define HW (512 * 512)
#define BS 16

__global__ __launch_bounds__(256) void dice_main(const float* __restrict__ logits,
                                                 const int* __restrict__ targets,
                                                 float* __restrict__ ws) {
    // 256 blocks per batch element; each thread handles 4 consecutive pixels.
    const int b = blockIdx.x >> 8;
    const int tid4 = ((blockIdx.x & 255) << 8) + threadIdx.x;  // 0..65535 per batch

    const float4* lg = reinterpret_cast<const float4*>(logits) + (size_t)b * NC * (HW / 4);
    const int4 t = reinterpret_cast<const int4*>(targets)[(size_t)b * (HW / 4) + tid4];

    float s1 = 0.f, inter = 0.f;
#pragma unroll
    for (int c = 0; c < NC; ++c) {
        float4 v = lg[(size_t)c * (HW / 4) + tid4];
        float sx = 1.f / (1.f + __expf(-v.x));
        float sy = 1.f / (1.f + __expf(-v.y));
        float sz = 1.f / (1.f + __expf(-v.z));
        float sw = 1.f / (1.f + __expf(-v.w));
        s1 += (sx + sy) + (sz + sw);
        inter += (t.x == c) ? sx : 0.f;
        inter += (t.y == c) ? sy : 0.f;
        inter += (t.z == c) ? sz : 0.f;
        inter += (t.w == c) ? sw : 0.f;
    }

    // wave-64 butterfly reduce
#pragma unroll
    for (int off = 32; off; off >>= 1) {
        s1 += __shfl_down(s1, off, 64);
        inter += __shfl_down(inter, off, 64);
    }

    __shared__ float sm[8];
    const int lane = threadIdx.x & 63;
    const int wid = threadIdx.x >> 6;
    if (lane == 0) {
        sm[wid] = s1;
        sm[4 + wid] = inter;
    }
    __syncthreads();
    if (threadIdx.x == 0) {
        float bs1 = (sm[0] + sm[1]) + (sm[2] + sm[3]);
        float bin = (sm[4] + sm[5]) + (sm[6] + sm[7]);
        atomicAdd(&ws[b], bs1);
        atomicAdd(&ws[BS + b], bin);
    }
}

__global__ void dice_final(const float* __restrict__ ws, float* __restrict__ out) {
    float sc = 0.f;
    if (threadIdx.x < BS) {
        float s1 = ws[threadIdx.x];
        float inter = ws[BS + threadIdx.x];
        sc = 2.f * (inter + 1.f) / (s1 + (float)HW + 1.f);
    }
#pragma unroll
    for (int off = 32; off; off >>= 1) sc += __shfl_down(sc, off, 64);
    if (threadIdx.x == 0) out[0] = 1.f - sc / (float)BS;
}

extern "C" void kernel_launch(void* const* d_in, const int* in_sizes, int n_in,
                              void* d_out, int out_size, void* d_ws, size_t ws_size,
                              hipStream_t stream) {
    const float* logits = (const float*)d_in[0];
    const int* targets = (const int*)d_in[1];
    float* out = (float*)d_out;
    float* ws = (float*)d_ws;

    hipMemsetAsync(ws, 0, 2 * BS * sizeof(float), stream);
    dice_main<<<BS * 256, 256, 0, stream>>>(logits, targets, ws);
    dice_final<<<1, 64, 0, stream>>>(ws, out);
}

// Round 3
// 61.526 us; speedup vs baseline: 1.6193x; 1.6193x over previous
//
#include <hip/hip_runtime.h>

#define NC 21
#define HW (512 * 512)
#define BS 16
// 256 blocks per batch * 256 threads * 4 px = 262144 px = HW

typedef float f32x4 __attribute__((ext_vector_type(4)));
typedef int i32x4 __attribute__((ext_vector_type(4)));

__global__ __launch_bounds__(256) void dice_main(const float* __restrict__ logits,
                                                 const int* __restrict__ targets,
                                                 float* __restrict__ ws) {
    const int b = blockIdx.x >> 8;
    const int tid4 = ((blockIdx.x & 255) << 8) + threadIdx.x;  // 0..65535 per batch

    const f32x4* lg = reinterpret_cast<const f32x4*>(logits) + (size_t)b * NC * (HW / 4);
    const i32x4 t = __builtin_nontemporal_load(
        reinterpret_cast<const i32x4*>(targets) + (size_t)b * (HW / 4) + tid4);

    float s1 = 0.f, inter = 0.f;
#pragma unroll
    for (int c = 0; c < NC; ++c) {
        f32x4 v = __builtin_nontemporal_load(&lg[(size_t)c * (HW / 4) + tid4]);
        // sigmoid(x) = rcp(1 + exp2(-x*log2e)) ; raw v_exp_f32 + v_rcp_f32
        float sx = __builtin_amdgcn_rcpf(1.f + __builtin_amdgcn_exp2f(v.x * -1.44269504f));
        float sy = __builtin_amdgcn_rcpf(1.f + __builtin_amdgcn_exp2f(v.y * -1.44269504f));
        float sz = __builtin_amdgcn_rcpf(1.f + __builtin_amdgcn_exp2f(v.z * -1.44269504f));
        float sw = __builtin_amdgcn_rcpf(1.f + __builtin_amdgcn_exp2f(v.w * -1.44269504f));
        s1 += (sx + sy) + (sz + sw);
        inter += (t.x == c) ? sx : 0.f;
        inter += (t.y == c) ? sy : 0.f;
        inter += (t.z == c) ? sz : 0.f;
        inter += (t.w == c) ? sw : 0.f;
    }

    // wave-64 reduce
#pragma unroll
    for (int off = 32; off; off >>= 1) {
        s1 += __shfl_down(s1, off, 64);
        inter += __shfl_down(inter, off, 64);
    }

    __shared__ float sm[8];
    const int lane = threadIdx.x & 63;
    const int wid = threadIdx.x >> 6;
    if (lane == 0) {
        sm[wid] = s1;
        sm[4 + wid] = inter;
    }
    __syncthreads();
    if (threadIdx.x == 0) {
        // per-block partials to unique slots -> no init / no atomics needed
        ws[blockIdx.x] = (sm[0] + sm[1]) + (sm[2] + sm[3]);
        ws[BS * 256 + blockIdx.x] = (sm[4] + sm[5]) + (sm[6] + sm[7]);
    }
}

__global__ __launch_bounds__(1024) void dice_final(const float* __restrict__ ws,
                                                   float* __restrict__ out) {
    // 16 waves; wave w reduces the 256 partials of batch w
    const int w = threadIdx.x >> 6;
    const int lane = threadIdx.x & 63;
    float s1 = 0.f, in = 0.f;
#pragma unroll
    for (int i = 0; i < 4; ++i) {
        const int idx = (w << 8) + (i << 6) + lane;
        s1 += ws[idx];
        in += ws[BS * 256 + idx];
    }
#pragma unroll
    for (int off = 32; off; off >>= 1) {
        s1 += __shfl_down(s1, off, 64);
        in += __shfl_down(in, off, 64);
    }
    __shared__ float sm[16];
    if (lane == 0) sm[w] = 2.f * (in + 1.f) / (s1 + (float)HW + 1.f);
    __syncthreads();
    if (threadIdx.x == 0) {
        float sc = 0.f;
#pragma unroll
        for (int i = 0; i < BS; ++i) sc += sm[i];
        out[0] = 1.f - sc * (1.f / BS);
    }
}

extern "C" void kernel_launch(void* const* d_in, const int* in_sizes, int n_in,
                              void* d_out, int out_size, void* d_ws, size_t ws_size,
                              hipStream_t stream) {
    const float* logits = (const float*)d_in[0];
    const int* targets = (const int*)d_in[1];
    float* out = (float*)d_out;
    float* ws = (float*)d_ws;

    dice_main<<<BS * 256, 256, 0, stream>>>(logits, targets, ws);
    dice_final<<<1, 1024, 0, stream>>>(ws, out);
}